// Round 4
// baseline (198.643 us; speedup 1.0000x reference)
//
#include <hip/hip_runtime.h>

// GRU fused, MI355X/gfx950 — round 6.
// r5 post-mortem: launch_bounds(512,4) = 128-VGPR cap + unroll-2 caused
// in-loop scratch spills (WRITE_SIZE 81MB, +16us). Fix: back to 4-wave
// blocks with a 256-VGPR budget (launch_bounds(256,2)), keep r5's lean
// step (operand-swap MFMA, packed b64 h-write, fully preloaded x, one
// barrier/step). 2 blocks/CU desync across barriers. Preload reassigned
// (r=i&15,t=i>>4) to kill the ~28-way init LDS write conflicts.

#define B_  16384
#define T_  28
#define F_  28
#define H_  128
#define C_  10
#define MB  16     // batch rows per block
#define LHS 136    // lh row stride in ushorts (272 B; balanced banks for b128/b64)
#define LXR 28     // lx row stride in ushorts (packed; b64-aligned, balanced banks)
#define LXT (MB*LXR)   // 448 ushorts per timestep

typedef short  short8  __attribute__((ext_vector_type(8)));
typedef short  short4v __attribute__((ext_vector_type(4)));
typedef float  f32x4   __attribute__((ext_vector_type(4)));

__device__ __forceinline__ unsigned short f2bf(float f) {   // RNE fp32->bf16
    unsigned u = __builtin_bit_cast(unsigned, f);
    u += 0x7fffu + ((u >> 16) & 1u);
    return (unsigned short)(u >> 16);
}
__device__ __forceinline__ float bf2f(unsigned short h) {
    unsigned u = ((unsigned)h) << 16;
    return __builtin_bit_cast(float, u);
}
__device__ __forceinline__ float fast_sig(float x) {        // 1/(1+e^-x)
    float e = __builtin_amdgcn_exp2f(x * -1.442695040888963f);
    return __builtin_amdgcn_rcpf(1.0f + e);
}
__device__ __forceinline__ float fast_tanh(float x) {       // 1 - 2/(1+e^{2x})
    float e = __builtin_amdgcn_exp2f(x * 2.885390081777927f);
    return 1.0f - 2.0f * __builtin_amdgcn_rcpf(1.0f + e);
}

__global__ __launch_bounds__(256, 2)
void gru_fused(const float* __restrict__ x,     // (B,T,F)
               const float* __restrict__ wk,    // (F,3H) = (28,384)
               const float* __restrict__ wrk,   // (H,3H) = (128,384)
               const float* __restrict__ bias,  // (2,3H)
               const float* __restrict__ dw,    // (H,C)
               const float* __restrict__ db,    // (C,)
               float* __restrict__ out)         // (B,C)
{
    // ---- LDS (~39.6 KB) ----
    __shared__ __align__(16) unsigned short lh[2][MB*LHS];      // 8704 B, double-buffered
    __shared__ __align__(16) unsigned short lx[T_*LXT + 8];     // 25104 B (+guard pad)
    __shared__ float ldw[H_*C_];                                // 5120 B
    __shared__ float llog[MB][C_];                              // 640 B

    const int tid  = threadIdx.x;
    const int base = blockIdx.x * MB;
    const int lane = tid & 63;
    const int wc   = tid >> 6;    // wave id 0..3 -> 32-column slice (2 x 16)
    const int n    = lane & 15;   // B-operand outer (batch) / D col
    const int q    = lane >> 4;   // MFMA quad

    // ---- loop-invariant weight fragments -> REGISTERS (120 VGPR/wave) ----
    // A-frag (weights): elem(lane,j) = W[k = kb*32 + q*8 + j][col], col = wc*32 + ut*16 + n
    short8 wz[2][4], wr[2][4], wh[2][4];   // W_rec per [ut][kb], gates z/r/h: 96 VGPR
    short8 xz[2], xr[2], xh[2];            // kernel (K pad 28->32): 24 VGPR
    #pragma unroll
    for (int ut = 0; ut < 2; ++ut) {
        const int col = wc*32 + ut*16 + n;
        #pragma unroll
        for (int kb = 0; kb < 4; ++kb) {
            const int k0 = kb*32 + q*8;
            short8 vz, vr, vh;
            #pragma unroll
            for (int j = 0; j < 8; ++j) {
                const float* wp = wrk + (size_t)(k0 + j)*384 + col;
                vz[j] = (short)f2bf(wp[0]);
                vr[j] = (short)f2bf(wp[128]);
                vh[j] = (short)f2bf(wp[256]);
            }
            wz[ut][kb] = vz; wr[ut][kb] = vr; wh[ut][kb] = vh;
        }
        short8 vz, vr, vh;
        #pragma unroll
        for (int j = 0; j < 8; ++j) {
            const int k = q*8 + j;
            if (k < F_) {
                const float* wp = wk + (size_t)k*384 + col;
                vz[j] = (short)f2bf(wp[0]);
                vr[j] = (short)f2bf(wp[128]);
                vh[j] = (short)f2bf(wp[256]);
            } else { vz[j] = 0; vr[j] = 0; vh[j] = 0; }
        }
        xz[ut] = vz; xr[ut] = vr; xh[ut] = vh;
    }

    // ---- biases -> registers (D rows = units) : 32 VGPR ----
    float bzv[2][4], brv[2][4], bxv[2][4], bhv[2][4];
    #pragma unroll
    for (int ut = 0; ut < 2; ++ut)
        #pragma unroll
        for (int reg = 0; reg < 4; ++reg) {
            const int u = wc*32 + ut*16 + q*4 + reg;
            bzv[ut][reg] = bias[u]       + bias[384 + u];   // bi_z + br_z
            brv[ut][reg] = bias[128 + u] + bias[512 + u];   // bi_r + br_r
            bxv[ut][reg] = bias[256 + u];                   // bi_h
            bhv[ut][reg] = bias[640 + u];                   // br_h
        }

    // ---- dense weights / h0 / full-x preload ----
    for (int i = tid; i < H_*C_; i += 256) ldw[i] = dw[i];
    for (int i = tid; i < MB*LHS/2; i += 256) ((unsigned*)lh[0])[i] = 0u;
    for (int i = tid; i < MB*T_; i += 256) {       // r fastest -> no same-bank pileup
        const int r = i & 15;
        const int t = i >> 4;
        const float* xp = x + (size_t)(base + r)*(T_*F_) + t*F_;
        unsigned short* dst = &lx[t*LXT + r*LXR];
        #pragma unroll
        for (int s4 = 0; s4 < 7; ++s4) {
            float4 a = *(const float4*)(xp + s4*4);
            short4v v;
            v[0]=(short)f2bf(a.x); v[1]=(short)f2bf(a.y);
            v[2]=(short)f2bf(a.z); v[3]=(short)f2bf(a.w);
            *(short4v*)(dst + s4*4) = v;
        }
    }
    if (tid == 0) {        // zero the guard pad
        *(short4v*)&lx[T_*LXT]     = (short4v){0,0,0,0};
        *(short4v*)&lx[T_*LXT + 4] = (short4v){0,0,0,0};
    }

    __syncthreads();   // init visible

    float hm[2][4];               // fp32 h master: units (wc*32+ut*16+q*4)+reg, batch n
    #pragma unroll
    for (int ut = 0; ut < 2; ++ut)
        #pragma unroll
        for (int r = 0; r < 4; ++r) hm[ut][r] = 0.f;

    const int rbase = n*LHS;      // h B-frag row base (loop-invariant)
    const int xoff  = n*LXR + q*8;
    const int wbase = n*LHS + wc*32 + q*4;   // h write base (ut adds 16)

    #pragma unroll 1
    for (int t = 0; t < T_; ++t) {
        const unsigned short* __restrict__ lhr = lh[t & 1];
        unsigned short* __restrict__ lhw = lh[(t + 1) & 1];
        const unsigned short* __restrict__ lxt = lx + t*LXT;

        // B-fragments (shared by both ut slices): h (4x b128) + x (2x b64)
        short8 hb[4]; short8 xbv;
        #pragma unroll
        for (int kb = 0; kb < 4; ++kb)
            hb[kb] = *(const short8*)&lhr[rbase + kb*32 + q*8];
        {
            short4v x0 = *(const short4v*)&lxt[xoff];
            short4v x1 = *(const short4v*)&lxt[xoff + 4];
            xbv = __builtin_shufflevector(x0, x1, 0,1,2,3,4,5,6,7);
        }

        f32x4 az[2], ag[2], ax[2], ah[2];
        #pragma unroll
        for (int ut = 0; ut < 2; ++ut) {
            az[ut] = (f32x4){bzv[ut][0], bzv[ut][1], bzv[ut][2], bzv[ut][3]};
            ag[ut] = (f32x4){brv[ut][0], brv[ut][1], brv[ut][2], brv[ut][3]};
            ax[ut] = (f32x4){bxv[ut][0], bxv[ut][1], bxv[ut][2], bxv[ut][3]};
            ah[ut] = (f32x4){bhv[ut][0], bhv[ut][1], bhv[ut][2], bhv[ut][3]};
            #pragma unroll
            for (int kb = 0; kb < 4; ++kb) {
                az[ut] = __builtin_amdgcn_mfma_f32_16x16x32_bf16(wz[ut][kb], hb[kb], az[ut], 0,0,0);
                ag[ut] = __builtin_amdgcn_mfma_f32_16x16x32_bf16(wr[ut][kb], hb[kb], ag[ut], 0,0,0);
                ah[ut] = __builtin_amdgcn_mfma_f32_16x16x32_bf16(wh[ut][kb], hb[kb], ah[ut], 0,0,0);
            }
            az[ut] = __builtin_amdgcn_mfma_f32_16x16x32_bf16(xz[ut], xbv, az[ut], 0,0,0);
            ag[ut] = __builtin_amdgcn_mfma_f32_16x16x32_bf16(xr[ut], xbv, ag[ut], 0,0,0);
            ax[ut] = __builtin_amdgcn_mfma_f32_16x16x32_bf16(xh[ut], xbv, ax[ut], 0,0,0);
        }

        // gates + h update; D layout: row = q*4+reg (unit), col = n (batch)
        #pragma unroll
        for (int ut = 0; ut < 2; ++ut) {
            float hn[4];
            #pragma unroll
            for (int reg = 0; reg < 4; ++reg) {
                float z  = fast_sig(az[ut][reg]);
                float r  = fast_sig(ag[ut][reg]);
                float hh = fast_tanh(ax[ut][reg] + r * ah[ut][reg]);
                float hv = hh + z * (hm[ut][reg] - hh);
                hm[ut][reg] = hv; hn[reg] = hv;
            }
            uint2 pk;
            pk.x = ((unsigned)f2bf(hn[1]) << 16) | (unsigned)f2bf(hn[0]);
            pk.y = ((unsigned)f2bf(hn[3]) << 16) | (unsigned)f2bf(hn[2]);
            *(uint2*)&lhw[wbase + ut*16] = pk;
        }

        __syncthreads();   // h_{t+1} published
    }

    // ---- dense + softmax epilogue (final h in lh[0]: last write t=27 -> (27+1)&1) ----
    if (tid < MB*C_) {
        const int row = tid / C_, c = tid - row*C_;
        float s = db[c];
        #pragma unroll
        for (int u0 = 0; u0 < H_; u0 += 8) {
            short8 hv = *(const short8*)&lh[0][row*LHS + u0];
            #pragma unroll
            for (int j = 0; j < 8; ++j)
                s += bf2f((unsigned short)hv[j]) * ldw[(u0+j)*C_ + c];
        }
        llog[row][c] = s;
    }
    __syncthreads();
    if (tid < MB) {
        const int row = tid;
        float m = llog[row][0];
        #pragma unroll
        for (int c = 1; c < C_; ++c) m = fmaxf(m, llog[row][c]);
        float e[C_], s = 0.f;
        #pragma unroll
        for (int c = 0; c < C_; ++c) {
            e[c] = __builtin_amdgcn_exp2f((llog[row][c] - m) * 1.442695040888963f);
            s += e[c];
        }
        const float inv = __builtin_amdgcn_rcpf(s);
        float* o = out + (size_t)(base + row)*C_;
        #pragma unroll
        for (int c = 0; c < C_; ++c) o[c] = e[c] * inv;
    }
}

extern "C" void kernel_launch(void* const* d_in, const int* in_sizes, int n_in,
                              void* d_out, int out_size, void* d_ws, size_t ws_size,
                              hipStream_t stream) {
    const float* x   = (const float*)d_in[0];
    const float* wk  = (const float*)d_in[1];
    const float* wrk = (const float*)d_in[2];
    const float* bs  = (const float*)d_in[3];
    const float* dw  = (const float*)d_in[4];
    const float* db  = (const float*)d_in[5];
    (void)in_sizes; (void)n_in; (void)out_size; (void)d_ws; (void)ws_size;
    gru_fused<<<dim3(B_/MB), dim3(256), 0, stream>>>(x, wk, wrk, bs, dw, db, (float*)d_out);
}

// Round 5
// 165.446 us; speedup vs baseline: 1.2007x; 1.2007x over previous
//
#include <hip/hip_runtime.h>

// GRU fused, MI355X/gfx950 — round 7.
// Cross-round evidence: spill traffic (WRITE_SIZE) tracks dur (r2 7.8MB/96us
// ... r6 61MB/133us); occupancy is secondary; 2 output tiles per wave (r2)
// beat 1 (r3) via intra-wave MFMA/VALU ILP.
// r7 = r5's lean step (operand-swap MFMA, packed b64 h-write, preloaded x,
// 1 barrier/step) + 256-reg budget (launch_bounds(512,2): live ~176, NO
// spills) + MB=32 as two batch tiles sharing the same weight registers.

#define B_  16384
#define T_  28
#define F_  28
#define H_  128
#define C_  10
#define MB  32     // batch rows per block (2 tiles of 16)
#define LHS 136    // lh row stride in ushorts (272 B; balanced banks for b128/b64)
#define LXR 28     // lx row stride in ushorts (packed; b64-aligned, balanced banks)
#define LXT (MB*LXR)   // 896 ushorts per timestep

typedef short  short8  __attribute__((ext_vector_type(8)));
typedef short  short4v __attribute__((ext_vector_type(4)));
typedef float  f32x4   __attribute__((ext_vector_type(4)));

__device__ __forceinline__ unsigned short f2bf(float f) {   // RNE fp32->bf16
    unsigned u = __builtin_bit_cast(unsigned, f);
    u += 0x7fffu + ((u >> 16) & 1u);
    return (unsigned short)(u >> 16);
}
__device__ __forceinline__ float bf2f(unsigned short h) {
    unsigned u = ((unsigned)h) << 16;
    return __builtin_bit_cast(float, u);
}
__device__ __forceinline__ float fast_sig(float x) {        // 1/(1+e^-x)
    float e = __builtin_amdgcn_exp2f(x * -1.442695040888963f);
    return __builtin_amdgcn_rcpf(1.0f + e);
}
__device__ __forceinline__ float fast_tanh(float x) {       // 1 - 2/(1+e^{2x})
    float e = __builtin_amdgcn_exp2f(x * 2.885390081777927f);
    return 1.0f - 2.0f * __builtin_amdgcn_rcpf(1.0f + e);
}

__global__ __launch_bounds__(512, 2)
void gru_fused(const float* __restrict__ x,     // (B,T,F)
               const float* __restrict__ wk,    // (F,3H) = (28,384)
               const float* __restrict__ wrk,   // (H,3H) = (128,384)
               const float* __restrict__ bias,  // (2,3H)
               const float* __restrict__ dw,    // (H,C)
               const float* __restrict__ db,    // (C,)
               float* __restrict__ out)         // (B,C)
{
    // ---- LDS (~74 KB) ----
    __shared__ __align__(16) unsigned short lh[2][MB*LHS];      // 17408 B, double-buffered
    __shared__ __align__(16) unsigned short lx[T_*LXT + 8];     // 50192 B (+guard pad)
    __shared__ float ldw[H_*C_];                                // 5120 B
    __shared__ float llog[MB][C_];                              // 1280 B

    const int tid  = threadIdx.x;
    const int base = blockIdx.x * MB;
    const int lane = tid & 63;
    const int wc   = tid >> 6;    // wave id 0..7 -> 16-column slice
    const int n    = lane & 15;   // B-operand outer (batch within tile) / D col
    const int q    = lane >> 4;   // MFMA quad
    const int col  = wc*16 + n;   // weight column (A operand)

    // ---- loop-invariant weight fragments -> REGISTERS (60 VGPR/wave) ----
    // A-frag (weights): elem(lane,j) = W[k = kb*32 + q*8 + j][col]
    short8 wzr[4], wrr[4], whr[4];   // W_rec per kb, gates z/r/h: 48 VGPR
    short8 xzr, xrr, xhr;            // kernel (K pad 28->32): 12 VGPR
    {
        #pragma unroll
        for (int kb = 0; kb < 4; ++kb) {
            const int k0 = kb*32 + q*8;
            short8 vz, vr, vh;
            #pragma unroll
            for (int j = 0; j < 8; ++j) {
                const float* wp = wrk + (size_t)(k0 + j)*384 + col;
                vz[j] = (short)f2bf(wp[0]);
                vr[j] = (short)f2bf(wp[128]);
                vh[j] = (short)f2bf(wp[256]);
            }
            wzr[kb] = vz; wrr[kb] = vr; whr[kb] = vh;
        }
        short8 vz, vr, vh;
        #pragma unroll
        for (int j = 0; j < 8; ++j) {
            const int k = q*8 + j;
            if (k < F_) {
                const float* wp = wk + (size_t)k*384 + col;
                vz[j] = (short)f2bf(wp[0]);
                vr[j] = (short)f2bf(wp[128]);
                vh[j] = (short)f2bf(wp[256]);
            } else { vz[j] = 0; vr[j] = 0; vh[j] = 0; }
        }
        xzr = vz; xrr = vr; xhr = vh;
    }

    // ---- biases -> registers (16 VGPR; D rows = units) ----
    float bzv[4], brv[4], bxv[4], bhv[4];
    #pragma unroll
    for (int reg = 0; reg < 4; ++reg) {
        const int u = wc*16 + q*4 + reg;
        bzv[reg] = bias[u]       + bias[384 + u];   // bi_z + br_z
        brv[reg] = bias[128 + u] + bias[512 + u];   // bi_r + br_r
        bxv[reg] = bias[256 + u];                   // bi_h
        bhv[reg] = bias[640 + u];                   // br_h
    }

    // ---- dense weights / h0 / full-x preload ----
    for (int i = tid; i < H_*C_; i += 512) ldw[i] = dw[i];
    for (int i = tid; i < MB*LHS/2; i += 512) ((unsigned*)lh[0])[i] = 0u;
    for (int i = tid; i < MB*T_; i += 512) {       // r fastest -> balanced LDS banks
        const int r = i & 31;
        const int t = i >> 5;
        const float* xp = x + (size_t)(base + r)*(T_*F_) + t*F_;
        unsigned short* dst = &lx[t*LXT + r*LXR];
        #pragma unroll
        for (int s4 = 0; s4 < 7; ++s4) {
            float4 a = *(const float4*)(xp + s4*4);
            short4v v;
            v[0]=(short)f2bf(a.x); v[1]=(short)f2bf(a.y);
            v[2]=(short)f2bf(a.z); v[3]=(short)f2bf(a.w);
            *(short4v*)(dst + s4*4) = v;
        }
    }
    if (tid == 0) {        // zero the guard pad
        *(short4v*)&lx[T_*LXT]     = (short4v){0,0,0,0};
        *(short4v*)&lx[T_*LXT + 4] = (short4v){0,0,0,0};
    }

    __syncthreads();   // init visible

    float hm[2][4];               // fp32 h master: unit wc*16+q*4+reg, batch mt*16+n
    #pragma unroll
    for (int mt = 0; mt < 2; ++mt)
        #pragma unroll
        for (int r = 0; r < 4; ++r) hm[mt][r] = 0.f;

    const int wbase = n*LHS + wc*16 + q*4;   // h write base (mt adds 16*LHS)

    #pragma unroll 1
    for (int t = 0; t < T_; ++t) {
        const unsigned short* __restrict__ lhr = lh[t & 1];
        unsigned short* __restrict__ lhw = lh[(t + 1) & 1];
        const unsigned short* __restrict__ lxt = lx + t*LXT;

        // B-fragments for both batch tiles: h (2x4 b128) + x (2x2 b64)
        short8 hb[2][4]; short8 xbv[2];
        #pragma unroll
        for (int mt = 0; mt < 2; ++mt) {
            const int rbase = (mt*16 + n)*LHS;
            #pragma unroll
            for (int kb = 0; kb < 4; ++kb)
                hb[mt][kb] = *(const short8*)&lhr[rbase + kb*32 + q*8];
            const int xoff = (mt*16 + n)*LXR + q*8;
            short4v x0 = *(const short4v*)&lxt[xoff];
            short4v x1 = *(const short4v*)&lxt[xoff + 4];
            xbv[mt] = __builtin_shufflevector(x0, x1, 0,1,2,3,4,5,6,7);
        }

        // MFMA both tiles (independent chains -> MFMA pipe stays fed while
        // the other tile's gates run on VALU)
        f32x4 az[2], ag[2], ax[2], ah[2];
        #pragma unroll
        for (int mt = 0; mt < 2; ++mt) {
            az[mt] = (f32x4){bzv[0], bzv[1], bzv[2], bzv[3]};
            ag[mt] = (f32x4){brv[0], brv[1], brv[2], brv[3]};
            ax[mt] = (f32x4){bxv[0], bxv[1], bxv[2], bxv[3]};
            ah[mt] = (f32x4){bhv[0], bhv[1], bhv[2], bhv[3]};
            #pragma unroll
            for (int kb = 0; kb < 4; ++kb) {
                az[mt] = __builtin_amdgcn_mfma_f32_16x16x32_bf16(wzr[kb], hb[mt][kb], az[mt], 0,0,0);
                ag[mt] = __builtin_amdgcn_mfma_f32_16x16x32_bf16(wrr[kb], hb[mt][kb], ag[mt], 0,0,0);
                ah[mt] = __builtin_amdgcn_mfma_f32_16x16x32_bf16(whr[kb], hb[mt][kb], ah[mt], 0,0,0);
            }
            az[mt] = __builtin_amdgcn_mfma_f32_16x16x32_bf16(xzr, xbv[mt], az[mt], 0,0,0);
            ag[mt] = __builtin_amdgcn_mfma_f32_16x16x32_bf16(xrr, xbv[mt], ag[mt], 0,0,0);
            ax[mt] = __builtin_amdgcn_mfma_f32_16x16x32_bf16(xhr, xbv[mt], ax[mt], 0,0,0);
        }

        // gates + h update; D layout: row = q*4+reg (unit), col = n (batch)
        #pragma unroll
        for (int mt = 0; mt < 2; ++mt) {
            float hn[4];
            #pragma unroll
            for (int reg = 0; reg < 4; ++reg) {
                float z  = fast_sig(az[mt][reg]);
                float r  = fast_sig(ag[mt][reg]);
                float hh = fast_tanh(ax[mt][reg] + r * ah[mt][reg]);
                float hv = hh + z * (hm[mt][reg] - hh);
                hm[mt][reg] = hv; hn[reg] = hv;
            }
            uint2 pk;
            pk.x = ((unsigned)f2bf(hn[1]) << 16) | (unsigned)f2bf(hn[0]);
            pk.y = ((unsigned)f2bf(hn[3]) << 16) | (unsigned)f2bf(hn[2]);
            *(uint2*)&lhw[wbase + mt*16*LHS] = pk;
        }

        __syncthreads();   // h_{t+1} published
    }

    // ---- dense + softmax epilogue (final h in lh[0]: last write t=27 -> (27+1)&1) ----
    if (tid < MB*C_) {
        const int row = tid / C_, c = tid - row*C_;
        float s = db[c];
        #pragma unroll
        for (int u0 = 0; u0 < H_; u0 += 8) {
            short8 hv = *(const short8*)&lh[0][row*LHS + u0];
            #pragma unroll
            for (int j = 0; j < 8; ++j)
                s += bf2f((unsigned short)hv[j]) * ldw[(u0+j)*C_ + c];
        }
        llog[row][c] = s;
    }
    __syncthreads();
    if (tid < MB) {
        const int row = tid;
        float m = llog[row][0];
        #pragma unroll
        for (int c = 1; c < C_; ++c) m = fmaxf(m, llog[row][c]);
        float e[C_], s = 0.f;
        #pragma unroll
        for (int c = 0; c < C_; ++c) {
            e[c] = __builtin_amdgcn_exp2f((llog[row][c] - m) * 1.442695040888963f);
            s += e[c];
        }
        const float inv = __builtin_amdgcn_rcpf(s);
        float* o = out + (size_t)(base + row)*C_;
        #pragma unroll
        for (int c = 0; c < C_; ++c) o[c] = e[c] * inv;
    }
}

extern "C" void kernel_launch(void* const* d_in, const int* in_sizes, int n_in,
                              void* d_out, int out_size, void* d_ws, size_t ws_size,
                              hipStream_t stream) {
    const float* x   = (const float*)d_in[0];
    const float* wk  = (const float*)d_in[1];
    const float* wrk = (const float*)d_in[2];
    const float* bs  = (const float*)d_in[3];
    const float* dw  = (const float*)d_in[4];
    const float* db  = (const float*)d_in[5];
    (void)in_sizes; (void)n_in; (void)out_size; (void)d_ws; (void)ws_size;
    gru_fused<<<dim3(B_/MB), dim3(512), 0, stream>>>(x, wk, wrk, bs, dw, db, (float*)d_out);
}